// Round 9
// baseline (396.290 us; speedup 1.0000x reference)
//
#include <hip/hip_runtime.h>

// Fixed problem shape
constexpr int BS = 16, F = 4086, C = 512, SPK = 2, L = 16, STEP = 8;
constexpr int T     = (F - 1) * STEP + L;   // 32696
constexpr int OUT_N = BS * SPK * T;         // 1046272
constexpr int WPAD  = 20;                   // padded W row stride (r1-proven: 0 bank conflicts)
constexpr int FR    = 6;                    // consecutive frames per wave; F = 6*681 exactly
constexpr int JPB   = F / FR;               // 681 wave-slots per batch row
constexpr int WAVES = 4, BLOCK = WAVES * 64;
constexpr int TOTW  = BS * JPB;             // 10896 waves
constexpr int GRID  = TOTW / WAVES;         // 2724 exactly

// ---- cross-lane helpers (verbatim from passing r2 kernel) -------------------
template <int CTRL>
__device__ __forceinline__ float dppq(float x) {
    int i = __builtin_bit_cast(int, x);
    i = __builtin_amdgcn_update_dpp(i, i, CTRL, 0xf, 0xf, true);
    return __builtin_bit_cast(float, i);
}
template <int OFF>
__device__ __forceinline__ float swz(float x) {
    int i = __builtin_bit_cast(int, x);
    i = __builtin_amdgcn_ds_swizzle(i, OFF);
    return __builtin_bit_cast(float, i);
}

// Ascending-mask butterfly fold of v[32] across 64 lanes (r2/r3-proven).
// Lane L ends with value index o(L) = 5-bit bit-reversal of L&31.
__device__ __forceinline__ float fold32(float v[32], int lane) {
    const bool h1 = lane & 1, h2 = lane & 2, h4 = lane & 4, h8 = lane & 8, h16 = lane & 16;
#pragma unroll
    for (int i = 0; i < 16; ++i) {               // m=1 : DPP quad_perm
        const float s = h1 ? v[i] : v[i + 16];
        const float k = h1 ? v[i + 16] : v[i];
        v[i] = k + dppq<0xB1>(s);
    }
#pragma unroll
    for (int i = 0; i < 8; ++i) {                // m=2 : DPP quad_perm
        const float s = h2 ? v[i] : v[i + 8];
        const float k = h2 ? v[i + 8] : v[i];
        v[i] = k + dppq<0x4E>(s);
    }
#pragma unroll
    for (int i = 0; i < 4; ++i) {                // m=4 : ds_swizzle
        const float s = h4 ? v[i] : v[i + 4];
        const float k = h4 ? v[i + 4] : v[i];
        v[i] = k + swz<0x101F>(s);
    }
#pragma unroll
    for (int i = 0; i < 2; ++i) {                // m=8 : ds_swizzle
        const float s = h8 ? v[i] : v[i + 2];
        const float k = h8 ? v[i + 2] : v[i];
        v[i] = k + swz<0x201F>(s);
    }
    {                                            // m=16 : ds_swizzle
        const float s = h16 ? v[0] : v[1];
        const float k = h16 ? v[1] : v[0];
        v[0] = k + swz<0x401F>(s);
    }
    return v[0] + __shfl_xor(v[0], 32, 64);
}

// ---- fused kernel: masked projection + overlap-and-add ----------------------
// Wave owns 6 consecutive frames f0..f0+5 of batch b. Sample t = f*8+l0 gets
// frame f (l=l0) + frame f-1 (l=8+l0). Interior samples (f = f0+1..f0+5) are
// wave-internal: partner value sits at o^8 = lane^2 (one quad_perm DPP).
// Head/tail 8 samples/spk use atomicAdd onto zeroed out (2 commutative adds).
__global__ __launch_bounds__(BLOCK, 4) void decoder_fused_ola_kernel(
    const float* __restrict__ inp,   // [BS][F][C]
    const float* __restrict__ mask,  // [BS][F][C][SPK]
    const float* __restrict__ W,     // [C][L]
    float* __restrict__ out)         // [BS][SPK][T], pre-zeroed
{
    __shared__ float w_lds[C * WPAD]; // 40 KB

    const int tid = threadIdx.x;

    // Stage W into LDS (r2 verbatim: coalesced, conflict-free padded rows)
    for (int r = tid; r < C; r += BLOCK) {
        const float4* src = reinterpret_cast<const float4*>(W + r * L);
        float4* d = reinterpret_cast<float4*>(w_lds + r * WPAD);
        d[0] = src[0]; d[1] = src[1]; d[2] = src[2]; d[3] = src[3];
    }
    __syncthreads();

    const int wave = tid >> 6, lane = tid & 63;
    const int wid  = blockIdx.x * WAVES + wave;
    const int b    = wid / JPB;
    const int j    = wid - b * JPB;
    const int f0   = j * FR;
    const size_t rowbase = (size_t)b * F + f0;

    // bit-reversed output index this lane owns after fold32 (o = s*16 + l)
    const int o = ((lane & 1) << 4) | (((lane >> 1) & 1) << 3) | (((lane >> 2) & 1) << 2)
                | (((lane >> 3) & 1) << 1) | ((lane >> 4) & 1);

    float  xiA[8], xiB[8];
    float2 xmA[8], xmB[8];

    auto load = [&](int q, float* xi, float2* xm) {
        const size_t row = rowbase + q;
        const float*  ir = inp + row * C;
        const float2* mr = reinterpret_cast<const float2*>(mask) + row * C;
#pragma unroll
        for (int i = 0; i < 8; ++i) {
            const int c = lane + 64 * i;   // dense: 256B / 512B per instruction
            xi[i] = ir[c];
            xm[i] = mr[c];
        }
    };

    auto compute = [&](const float* xi, const float2* xm) -> float {
        float v[32];
#pragma unroll
        for (int jj = 0; jj < 32; ++jj) v[jj] = 0.f;
#pragma unroll
        for (int i = 0; i < 8; ++i) {
            const int c  = lane + 64 * i;
            const float p0 = xi[i] * xm[i].x;
            const float p1 = xi[i] * xm[i].y;
            const float4* wr = reinterpret_cast<const float4*>(&w_lds[c * WPAD]);
#pragma unroll
            for (int q = 0; q < 4; ++q) {
                const float4 wv = wr[q];
                v[4*q+0]    = fmaf(p0, wv.x, v[4*q+0]);
                v[4*q+1]    = fmaf(p0, wv.y, v[4*q+1]);
                v[4*q+2]    = fmaf(p0, wv.z, v[4*q+2]);
                v[4*q+3]    = fmaf(p0, wv.w, v[4*q+3]);
                v[16+4*q+0] = fmaf(p1, wv.x, v[16+4*q+0]);
                v[16+4*q+1] = fmaf(p1, wv.y, v[16+4*q+1]);
                v[16+4*q+2] = fmaf(p1, wv.z, v[16+4*q+2]);
                v[16+4*q+3] = fmaf(p1, wv.w, v[16+4*q+3]);
            }
        }
        return fold32(v, lane);
    };

    // depth-2 pipeline over 6 frames (static indices throughout)
    float v0, v1, v2, v3, v4, v5;
    load(0, xiA, xmA);
    load(1, xiB, xmB);
    v0 = compute(xiA, xmA); load(2, xiA, xmA);
    v1 = compute(xiB, xmB); load(3, xiB, xmB);
    v2 = compute(xiA, xmA); load(4, xiA, xmA);
    v3 = compute(xiB, xmB); load(5, xiB, xmB);
    v4 = compute(xiA, xmA);
    v5 = compute(xiB, xmB);

    // partner values: o^8 lives at lane^2 (quad_perm DPP, pure VALU)
    const float p0 = dppq<0x4E>(v0), p1 = dppq<0x4E>(v1), p2 = dppq<0x4E>(v2),
                p3 = dppq<0x4E>(v3), p4 = dppq<0x4E>(v4);

    const int s  = o >> 4;          // speaker
    const int l0 = o & 7;
    float* ob = out + (size_t)(b * SPK + s) * T + (size_t)f0 * STEP;

    if (lane < 32) {
        if ((o & 8) == 0) {
            // interior: frames f0+1..f0+5 finalized in-wave
            ob[1 * 8 + l0] = v1 + p0;
            ob[2 * 8 + l0] = v2 + p1;
            ob[3 * 8 + l0] = v3 + p2;
            ob[4 * 8 + l0] = v4 + p3;
            ob[5 * 8 + l0] = v5 + p4;
            // head: frame f0, l = l0  ->  t = f0*8 + l0
            atomicAdd(&ob[l0], v0);
        } else {
            // tail: frame f0+5, l = 8+l0  ->  t = (f0+6)*8 + l0
            atomicAdd(&ob[48 + l0], v5);
        }
    }
}

extern "C" void kernel_launch(void* const* d_in, const int* in_sizes, int n_in,
                              void* d_out, int out_size, void* d_ws, size_t ws_size,
                              hipStream_t stream) {
    const float* inp  = (const float*)d_in[0];
    const float* mask = (const float*)d_in[1];
    const float* W    = (const float*)d_in[2];
    float* out = (float*)d_out;

    hipMemsetAsync(out, 0, (size_t)OUT_N * sizeof(float), stream);
    decoder_fused_ola_kernel<<<GRID, BLOCK, 0, stream>>>(inp, mask, W, out);
}

// Round 10
// 88.646 us; speedup vs baseline: 4.4705x; 4.4705x over previous
//
#include <hip/hip_runtime.h>

// Fixed problem shape
constexpr int BS = 16, F = 4086, C = 512, SPK = 2, L = 16, STEP = 8;
constexpr int T     = (F - 1) * STEP + L;   // 32696
constexpr int ROWS  = BS * F;               // 65376
constexpr int OUT_N = BS * SPK * T;         // 1046272
constexpr int OUT4  = OUT_N / 4;            // 261568
constexpr int WAVES = 4, BLOCK = WAVES * 64;
constexpr int FR  = 4;                      // frames per wave (r2-proven pipeline)
constexpr int FPB = WAVES * FR;             // 16 frames per block
constexpr int GRID_A = ROWS / FPB;          // 4086 exactly

typedef float f32x4 __attribute__((ext_vector_type(4)));

// ---- cross-lane helpers (verbatim from passing r2 kernel) -------------------
template <int CTRL>
__device__ __forceinline__ float dppq(float x) {
    int i = __builtin_bit_cast(int, x);
    i = __builtin_amdgcn_update_dpp(i, i, CTRL, 0xf, 0xf, true);
    return __builtin_bit_cast(float, i);
}
template <int OFF>
__device__ __forceinline__ float swz(float x) {
    int i = __builtin_bit_cast(int, x);
    i = __builtin_amdgcn_ds_swizzle(i, OFF);
    return __builtin_bit_cast(float, i);
}

// Ascending-mask butterfly fold of v[32] across 64 lanes (r2-proven).
// Lane L ends with value index o(L) = 5-bit bit-reversal of L&31.
__device__ __forceinline__ float fold32(float v[32], int lane) {
    const bool h1 = lane & 1, h2 = lane & 2, h4 = lane & 4, h8 = lane & 8, h16 = lane & 16;
#pragma unroll
    for (int i = 0; i < 16; ++i) {               // m=1 : DPP quad_perm
        const float s = h1 ? v[i] : v[i + 16];
        const float k = h1 ? v[i + 16] : v[i];
        v[i] = k + dppq<0xB1>(s);
    }
#pragma unroll
    for (int i = 0; i < 8; ++i) {                // m=2 : DPP quad_perm
        const float s = h2 ? v[i] : v[i + 8];
        const float k = h2 ? v[i + 8] : v[i];
        v[i] = k + dppq<0x4E>(s);
    }
#pragma unroll
    for (int i = 0; i < 4; ++i) {                // m=4 : ds_swizzle
        const float s = h4 ? v[i] : v[i + 4];
        const float k = h4 ? v[i + 4] : v[i];
        v[i] = k + swz<0x101F>(s);
    }
#pragma unroll
    for (int i = 0; i < 2; ++i) {                // m=8 : ds_swizzle
        const float s = h8 ? v[i] : v[i + 2];
        const float k = h8 ? v[i + 2] : v[i];
        v[i] = k + swz<0x201F>(s);
    }
    {                                            // m=16 : ds_swizzle
        const float s = h16 ? v[0] : v[1];
        const float k = h16 ? v[1] : v[0];
        v[0] = k + swz<0x401F>(s);
    }
    return v[0] + __shfl_xor(v[0], 32, 64);
}

__device__ __forceinline__ unsigned pk_bf16(float a, float b) {
    // dword: lo = bf16_rne(a), hi = bf16_rne(b)
    unsigned ua = __builtin_bit_cast(unsigned, a);
    unsigned ub = __builtin_bit_cast(unsigned, b);
    ua += 0x7fffu + ((ua >> 16) & 1u);
    ub += 0x7fffu + ((ub >> 16) & 1u);
    return (ua >> 16) | (ub & 0xffff0000u);
}

// ---- kernel A: masked projection -> proj[row][32] ---------------------------
// r2 structure verbatim; only the W-in-LDS representation changed:
// wpk4[q*256 + c2] (uint4, 16 KB) — dword j packs {W[c2][4q+j], W[c2+256][4q+j]}
// as bf16 (lo/hi). Lane reads wpk4[q*256 + lane+64i]: byte addr = lane*16+const
// -> contiguous 1024 B per ds_read_b128, conflict-free, 16B-aligned.
__global__ __launch_bounds__(BLOCK, 2) void decoder_proj_kernel(
    const float* __restrict__ inp,   // [BS][F][C]
    const float* __restrict__ mask,  // [BS][F][C][SPK]
    const float* __restrict__ W,     // [C][L]
    float* __restrict__ dst)         // proj[ROWS][32]
{
    __shared__ uint4 wpk4[4 * 256];  // 16 KB

    const int tid = threadIdx.x;

    // Stage: thread t packs channel pair (t, t+256). Coalesced 64B/thread reads.
    {
        const float4* r0 = reinterpret_cast<const float4*>(W + tid * L);
        const float4* r1 = reinterpret_cast<const float4*>(W + (tid + 256) * L);
#pragma unroll
        for (int q = 0; q < 4; ++q) {
            const float4 a = r0[q], b = r1[q];
            uint4 d;
            d.x = pk_bf16(a.x, b.x);
            d.y = pk_bf16(a.y, b.y);
            d.z = pk_bf16(a.z, b.z);
            d.w = pk_bf16(a.w, b.w);
            wpk4[q * 256 + tid] = d;   // ds_write_b128, aligned
        }
    }
    __syncthreads();

    const int wave = tid >> 6, lane = tid & 63;
    const int row0 = blockIdx.x * FPB + wave * FR;

    // bit-reversed output index this lane owns after fold32 (o = s*16 + l)
    const int o = ((lane & 1) << 4) | (((lane >> 1) & 1) << 3) | (((lane >> 2) & 1) << 2)
                | (((lane >> 3) & 1) << 1) | ((lane >> 4) & 1);

    float  xiA[8], xiB[8];
    float2 xmA[8], xmB[8];

    auto load = [&](int row, float* xi, float2* xm) {
        const float*  ir = inp + (size_t)row * C;
        const float2* mr = reinterpret_cast<const float2*>(mask) + (size_t)row * C;
#pragma unroll
        for (int i = 0; i < 8; ++i) {
            const int c = lane + 64 * i;   // dense: 256B / 512B per instruction
            xi[i] = ir[c];
            xm[i] = mr[c];
        }
    };

    auto compute = [&](const float* xi, const float2* xm) -> float {
        float v[32];
#pragma unroll
        for (int j = 0; j < 32; ++j) v[j] = 0.f;
#pragma unroll
        for (int i = 0; i < 4; ++i) {
            const int c2 = lane + 64 * i;          // pairs (c2, c2+256)
            const float p0lo = xi[i]     * xm[i].x;
            const float p1lo = xi[i]     * xm[i].y;
            const float p0hi = xi[i + 4] * xm[i + 4].x;
            const float p1hi = xi[i + 4] * xm[i + 4].y;
#pragma unroll
            for (int q = 0; q < 4; ++q) {
                const uint4 wd = wpk4[q * 256 + c2];   // ds_read_b128, conflict-free
                const unsigned dj[4] = {wd.x, wd.y, wd.z, wd.w};
#pragma unroll
                for (int j = 0; j < 4; ++j) {
                    const int l = 4 * q + j;
                    const float wlo = __builtin_bit_cast(float, dj[j] << 16);
                    const float whi = __builtin_bit_cast(float, dj[j] & 0xffff0000u);
                    v[l]      = fmaf(p0lo, wlo, v[l]);
                    v[l]      = fmaf(p0hi, whi, v[l]);
                    v[16 + l] = fmaf(p1lo, wlo, v[16 + l]);
                    v[16 + l] = fmaf(p1hi, whi, v[16 + l]);
                }
            }
        }
        return fold32(v, lane);
    };

    auto store = [&](int row, float val) {
        if (lane < 32) dst[(size_t)row * 32 + o] = val;  // 128B contiguous per wave
    };

    // depth-2 double-buffered pipeline over FR=4 frames (r2 verbatim)
    load(row0 + 0, xiA, xmA);
    load(row0 + 1, xiB, xmB);
    store(row0 + 0, compute(xiA, xmA));
    load(row0 + 2, xiA, xmA);
    store(row0 + 1, compute(xiB, xmB));
    load(row0 + 3, xiB, xmB);
    store(row0 + 2, compute(xiA, xmA));
    store(row0 + 3, compute(xiB, xmB));
}

// ---- kernel B: vectorized overlap-and-add gather (r8-proven) ----------------
__global__ __launch_bounds__(256) void overlap_add4_kernel(
    const float* __restrict__ proj,  // [ROWS][32]  (32 = s*16 + l)
    float* __restrict__ out)         // [BS][SPK][T]
{
    const int i4 = blockIdx.x * blockDim.x + threadIdx.x;
    if (i4 >= OUT4) return;
    const int t4 = i4 * 4;                 // T divisible by 4
    const int b = t4 / (SPK * T);
    const int r = t4 - b * (SPK * T);
    const int s = r / T;
    const int t = r - s * T;               // t % 4 == 0
    const int f0 = t >> 3, l0 = t & 7;     // l0 in {0,4}
    f32x4 acc = {0.f, 0.f, 0.f, 0.f};
    if (t < F * STEP)
        acc = *reinterpret_cast<const f32x4*>(&proj[(size_t)(b * F + f0) * 32 + s * 16 + l0]);
    if (t >= STEP) {
        const f32x4 p = *reinterpret_cast<const f32x4*>(&proj[(size_t)(b * F + f0 - 1) * 32 + s * 16 + 8 + l0]);
        acc += p;
    }
    *reinterpret_cast<f32x4*>(&out[t4]) = acc;
}

extern "C" void kernel_launch(void* const* d_in, const int* in_sizes, int n_in,
                              void* d_out, int out_size, void* d_ws, size_t ws_size,
                              hipStream_t stream) {
    const float* inp  = (const float*)d_in[0];
    const float* mask = (const float*)d_in[1];
    const float* W    = (const float*)d_in[2];
    float* out = (float*)d_out;

    float* proj = (float*)d_ws;   // 8.37 MB needed; ws is ample
    decoder_proj_kernel<<<GRID_A, BLOCK, 0, stream>>>(inp, mask, W, proj);
    overlap_add4_kernel<<<(OUT4 + 255) / 256, 256, 0, stream>>>(proj, out);
}